// Round 17
// baseline (114.487 us; speedup 1.0000x reference)
//
#include <hip/hip_runtime.h>

// FTDisentangledMHA: B=8, S=512, D=1024, H=16, Wd=64, MAX_REL=512 (span==S)
// scores(i,j) = scale*(q_i.k_j + q_i.pk[d] + k_j.pq[d]), d = i-j+511 (never clipped).
// q,pq pre-scaled by scale*log2e; softmax = exp2 with fixed max M=3.
// R17: attn occupancy 2->3 blocks/CU via hybrid 8-slot pk ring (LDS 56.3->47.8KB):
// per jt, dblks [W+4,W+7] come from the ring (staged last jt), dblks [W,W+3] are read
// direct from global AND DMA'd into slots (W..W+3)&7 for the next jt. pq stays direct.

typedef __bf16 bf16_t;
typedef __bf16 bf16x8 __attribute__((ext_vector_type(8)));
typedef __bf16 bf16x4 __attribute__((ext_vector_type(4)));
typedef float  f32x4  __attribute__((ext_vector_type(4)));

#define MFMA16(a, b, c) __builtin_amdgcn_mfma_f32_16x16x32_bf16((a), (b), (c), 0, 0, 0)
#define S2SCALE 0.10411754f   // (1/sqrt(192)) * log2(e)
#define MCONST  4.3280851f    // 3 * log2(e)

__device__ __forceinline__ void gload_lds16(const bf16_t* g, bf16_t* lds) {
  __builtin_amdgcn_global_load_lds(
      (const __attribute__((address_space(1))) void*)g,
      (__attribute__((address_space(3))) void*)lds, 16, 0, 0);
}

// ---------------------------------------------------------------- fp32 -> bf16 (all 5 arrays)
__global__ __launch_bounds__(256) void cvt_all(
    const float* __restrict__ x, const float* __restrict__ rel,
    const float* __restrict__ wq, const float* __restrict__ wk, const float* __restrict__ wv,
    bf16_t* __restrict__ out) {
  const size_t i = ((size_t)blockIdx.x * 256 + threadIdx.x) * 8;
  const float* src; size_t off;
  if (i < 4194304) { src = x; off = i; }
  else {
    size_t j = i - 4194304; int sel = (int)(j >> 20); off = j & 1048575;
    src = sel == 0 ? wq : sel == 1 ? wk : sel == 2 ? wv : rel;
  }
  float4 v0 = *reinterpret_cast<const float4*>(src + off);
  float4 v1 = *reinterpret_cast<const float4*>(src + off + 4);
  bf16x8 o;
  o[0] = (bf16_t)v0.x; o[1] = (bf16_t)v0.y; o[2] = (bf16_t)v0.z; o[3] = (bf16_t)v0.w;
  o[4] = (bf16_t)v1.x; o[5] = (bf16_t)v1.y; o[6] = (bf16_t)v1.z; o[7] = (bf16_t)v1.w;
  *reinterpret_cast<bf16x8*>(out + i) = o;
}

// ------------------------------------------------- 128x256-tile 8-phase projection GEMM
// 448 blocks (2/CU). Epilogue writes FRAGMENT-ordered outputs (reader: attn_v7):
//  kind 1 (q,k): flat = (((b16h)*32 + (j>>4))*2 + ks)*512 + ((j&15)|(kg<<4))*8 + e
//  kind 3 (pk,pq): flat = ((h*64 + (d>>4))*2 + ks)*512 + ((d&15)|(kg<<4))*8 + e
//  kind 2 (v): flat = (((b16h)*16 + (j>>5))*4 + n2)*512 + ((w&15)|(((j>>3)&3)<<4))*8 + (j&7)
__device__ __forceinline__ void stage_tileB(const bf16_t* base, int T, bf16_t* lds, int tid) {
#pragma unroll
  for (int i = 0; i < 2; ++i) {
    const int c = tid + i * 512;
    const int row = c >> 2, kg = (c & 3) ^ (row & 3);
    gload_lds16(base + (size_t)row * 1024 + T * 32 + kg * 8, lds + c * 8);
  }
}
__device__ __forceinline__ void stage_tileA(const bf16_t* base, int T, bf16_t* lds, int tid) {
  const int row = tid >> 2, kg = (tid & 3) ^ (row & 3);
  gload_lds16(base + (size_t)row * 1024 + T * 32 + kg * 8, lds + tid * 8);
}

#define VMW2 asm volatile("s_waitcnt vmcnt(2)" ::: "memory")
#define VMW0 asm volatile("s_waitcnt vmcnt(0)" ::: "memory")
#define NOPS ((void)0)

// phase: 2 A-frags (FH half of the wave's 64 rows) x 4 B-frags = 8 MFMA
#define PH_BODY(AB, BB, FH, READB, STAGE_STMT, WAIT_STMT)                               \
  {                                                                                     \
    if (READB) {                                                                        \
      _Pragma("unroll") for (int n_ = 0; n_ < 4; ++n_)                                  \
        bfr[n_] = *reinterpret_cast<const bf16x8*>(                                     \
            (BB) + (((wn * 64 + n_ * 16 + li) * 4 + (gr ^ (li & 3))) * 8));             \
    }                                                                                   \
    bf16x8 af_[2];                                                                      \
    _Pragma("unroll") for (int a_ = 0; a_ < 2; ++a_)                                    \
      af_[a_] = *reinterpret_cast<const bf16x8*>(                                       \
          (AB) + (((wm * 64 + ((FH) * 2 + a_) * 16 + li) * 4 + (gr ^ (li & 3))) * 8));  \
    STAGE_STMT;                                                                         \
    __builtin_amdgcn_s_barrier();                                                       \
    asm volatile("s_waitcnt lgkmcnt(0)" ::: "memory");                                  \
    __builtin_amdgcn_sched_barrier(0);                                                  \
    __builtin_amdgcn_s_setprio(1);                                                      \
    _Pragma("unroll") for (int a_ = 0; a_ < 2; ++a_)                                    \
      _Pragma("unroll") for (int n_ = 0; n_ < 4; ++n_)                                  \
        acc[(FH) * 2 + a_][n_] = MFMA16(af_[a_], bfr[n_], acc[(FH) * 2 + a_][n_]);      \
    __builtin_amdgcn_s_setprio(0);                                                      \
    WAIT_STMT;                                                                          \
    __builtin_amdgcn_s_barrier();                                                       \
    __builtin_amdgcn_sched_barrier(0);                                                  \
  }

__global__ __launch_bounds__(512, 2) void gemm_qkv(
    const bf16_t* __restrict__ xb, const bf16_t* __restrict__ reb,
    const bf16_t* __restrict__ wqb, const bf16_t* __restrict__ wkb, const bf16_t* __restrict__ wvb,
    const float* __restrict__ bq, const float* __restrict__ bk, const float* __restrict__ bv,
    bf16_t* __restrict__ qF, bf16_t* __restrict__ kF, bf16_t* __restrict__ vF,
    bf16_t* __restrict__ pkF, bf16_t* __restrict__ pqF) {
  __shared__ bf16_t Abuf[2][4096];   // 128 x 32
  __shared__ bf16_t Bbuf[2][8192];   // 256 x 32

  const int bid0 = blockIdx.x;
  const int bid = (bid0 & 7) * 56 + (bid0 >> 3);  // 448 = 8*56, bijective XCD chunks
  const int tid = threadIdx.x;
  const int wave = tid >> 6;
  const int wm = wave >> 2, wn = wave & 3;
  const int l = tid & 63, li = l & 15, gr = l >> 4;

  const bf16_t* Abase; const bf16_t* Bbase; const float* bias; float sc;
  bf16_t* Cout; int row0, col0, kind;
  if (bid < 384) {  // main: x (4096 rows, 32 tiles of 128) x [Wq|Wk|Wv] (3072)
    const int bx = bid / 12, by = bid % 12;
    Abase = xb + (size_t)bx * 131072; row0 = bx * 128;
    const int wsel = by >> 2;
    Bbase = (wsel == 0 ? wqb : wsel == 1 ? wkb : wvb) + (size_t)(by & 3) * 262144;
    bias = wsel == 0 ? bq : wsel == 1 ? bk : bv;
    sc = wsel == 0 ? S2SCALE : 1.f;
    Cout = wsel == 0 ? qF : wsel == 1 ? kF : vF;
    kind = wsel == 2 ? 2 : 1;
    col0 = (by & 3) * 256;
  } else {  // pos: re (1024 rows, 8 tiles) x [Wk|Wq] (2048)
    const int p = bid - 384;
    const int bx = p >> 3, by = p & 7;
    Abase = reb + (size_t)bx * 131072; row0 = bx * 128;
    const int wsel = by >> 2;
    Bbase = (wsel == 0 ? wkb : wqb) + (size_t)(by & 3) * 262144;
    bias = wsel == 0 ? bk : bq;
    sc = wsel == 0 ? 1.f : S2SCALE;
    Cout = wsel == 0 ? pkF : pqF;
    kind = 3;
    col0 = (by & 3) * 256;
  }

  f32x4 acc[4][4] = {};
  bf16x8 bfr[4];

  // prologue: A0(1), B0(2), B1(2) in flight; vmcnt(2) waits A0+B0, leaves B1 flying
  stage_tileA(Abase, 0, Abuf[0], tid);
  stage_tileB(Bbase, 0, Bbuf[0], tid);
  stage_tileB(Bbase, 1, Bbuf[1], tid);
  VMW2;
  __builtin_amdgcn_s_barrier();
  __builtin_amdgcn_sched_barrier(0);

  for (int t = 0; t < 15; ++t) {
    const int T0 = 2 * t;
    PH_BODY(Abuf[0], Bbuf[0], 0, true,  stage_tileA(Abase, T0 + 1, Abuf[1], tid), NOPS);
    PH_BODY(Abuf[0], Bbuf[0], 1, false, stage_tileB(Bbase, T0 + 2, Bbuf[0], tid), VMW2);
    PH_BODY(Abuf[1], Bbuf[1], 0, true,  stage_tileA(Abase, T0 + 2, Abuf[0], tid), NOPS);
    PH_BODY(Abuf[1], Bbuf[1], 1, false, stage_tileB(Bbase, T0 + 3, Bbuf[1], tid), VMW2);
  }
  // peeled t=15 (tiles 30,31): only A(31) left to stage
  PH_BODY(Abuf[0], Bbuf[0], 0, true,  stage_tileA(Abase, 31, Abuf[1], tid), NOPS);
  PH_BODY(Abuf[0], Bbuf[0], 1, false, NOPS, VMW0);
  PH_BODY(Abuf[1], Bbuf[1], 0, true,  NOPS, NOPS);
  PH_BODY(Abuf[1], Bbuf[1], 1, false, NOPS, NOPS);

  // epilogue: fragment-ordered stores
#pragma unroll
  for (int a = 0; a < 4; ++a)
#pragma unroll
    for (int n = 0; n < 4; ++n) {
      const int col = col0 + wn * 64 + n * 16 + li;
      const int h_ = col >> 6, kk = col & 63;
      const float bv_ = bias[col];
      const int rowb = row0 + wm * 64 + a * 16 + gr * 4;
      if (kind == 2) {
        bf16x4 ov;
#pragma unroll
        for (int r = 0; r < 4; ++r) ov[r] = (bf16_t)((acc[a][n][r] + bv_) * sc);
        const int j = rowb & 511, b_ = rowb >> 9;
        const size_t flat = ((((size_t)(b_ * 16 + h_) * 16 + (j >> 5)) * 4 + (kk >> 4)) * 512) +
                            ((size_t)((kk & 15) | (((j >> 3) & 3) << 4))) * 8 + (j & 7);
        *reinterpret_cast<bf16x4*>(Cout + flat) = ov;
      } else {
        const int ks = kk >> 5, kg3 = (kk >> 3) & 3, e = kk & 7;
#pragma unroll
        for (int r = 0; r < 4; ++r) {
          const int row = rowb + r;
          const int blk = (kind == 1) ? (((row >> 9) * 16 + h_) * 32 + ((row & 511) >> 4))
                                      : (h_ * 64 + (row >> 4));
          const size_t flat = ((size_t)blk * 2 + ks) * 512 + ((row & 15) | (kg3 << 4)) * 8 + e;
          Cout[flat] = (bf16_t)((acc[a][n][r] + bv_) * sc);
        }
      }
    }
}

// ---------------------------------------------------------------- fused attention
// 1024 blocks = (b,h,qt); 4 waves. Hybrid 8-slot pk ring: dblks [W+4,W+7] from ring,
// [W,W+3] direct from global + DMA'd into slots (W..W+3)&7 for next jt. pq direct.
__global__ __launch_bounds__(256, 2) void attn_v7(
    const bf16_t* __restrict__ qF, const bf16_t* __restrict__ kF,
    const bf16_t* __restrict__ vF, const bf16_t* __restrict__ pkF,
    const bf16_t* __restrict__ pqF, float* __restrict__ out) {
  const int bid0 = blockIdx.x;
  const int bid = (bid0 & 7) * 128 + (bid0 >> 3);  // XCD-contiguous (b,h)
  const int qt = bid & 7;
  const int h = (bid >> 3) & 15;
  const int b = bid >> 7;
  const int i0 = qt * 64;
  const int tid = threadIdx.x;
  const int l = tid & 63;
  const int w = tid >> 6;
  const int li = l & 15, gr = l >> 4;

  __shared__ bf16_t pkS[8192];        // 8 slots x 1024 elems (dblk&7)         16 KB
  __shared__ bf16_t Pl[4][1024];      // per-wave P A-frags (kchunk-swizzled)   8 KB
  __shared__ bf16_t DcpT[4][80][20];  // per-wave c2p [u_local][ip]           12.8 KB
  __shared__ bf16_t D2p[64][84];      // p2c [jj][ii+16] (unguarded)          10.5 KB

  const bf16_t* qFb = qF + (size_t)(b * 16 + h) * 32768;
  const bf16_t* kFb = kF + (size_t)(b * 16 + h) * 32768;
  const bf16_t* vFb = vF + (size_t)(b * 16 + h) * 32768;
  const bf16_t* pkFb = pkF + (size_t)h * 65536;
  const bf16_t* pqFb = pqF + (size_t)h * 65536;

  // Q A-frags (rows i0 + w*16 .. +15), coalesced
  const bf16x8 aq0 = *reinterpret_cast<const bf16x8*>(qFb + ((size_t)(qt * 4 + w) * 2 + 0) * 512 + l * 8);
  const bf16x8 aq1 = *reinterpret_cast<const bf16x8*>(qFb + ((size_t)(qt * 4 + w) * 2 + 1) * 512 + l * 8);

  // prologue: stage jt=0's RING half [W0+4 .. W0+7] (2 chunks/thread)
  {
    const int W0 = 4 * qt + 28;
#pragma unroll
    for (int i2 = 0; i2 < 2; ++i2) {
      const int c = i2 * 256 + tid;         // 0..511
      const int dblk = W0 + 4 + (c >> 7);
      const int inner = c & 127;
      const int slot = dblk & 7;
      gload_lds16(pkFb + (size_t)dblk * 1024 + inner * 8, pkS + slot * 1024 + inner * 8);
    }
  }

  f32x4 acc[4] = {};
  float lsum[4] = {0.f, 0.f, 0.f, 0.f};

  for (int jt = 0; jt < 8; ++jt) {
    const int W = 4 * qt - 4 * jt + 28;   // window base dblk, in [0,56]

    // top barrier: ring slots for this jt staged; prev jt's D2p reads done
    VMW0;
    __builtin_amdgcn_s_barrier();
    __builtin_amdgcn_sched_barrier(0);

    // DMA dblks [W..W+3] into slots (W..W+3)&7 — ring half of NEXT jt's window
    if (jt < 7) {
#pragma unroll
      for (int i2 = 0; i2 < 2; ++i2) {
        const int c = i2 * 256 + tid;       // 0..511
        const int dblk = W + (c >> 7);
        const int inner = c & 127;
        const int slot = dblk & 7;
        gload_lds16(pkFb + (size_t)dblk * 1024 + inner * 8, pkS + slot * 1024 + inner * 8);
      }
    }

    // K frags for QK^T (static indices only)
    bf16x8 kA[4][2];
#pragma unroll
    for (int jb = 0; jb < 4; ++jb)
#pragma unroll
      for (int ks = 0; ks < 2; ++ks)
        kA[jb][ks] = *reinterpret_cast<const bf16x8*>(
            kFb + ((size_t)(jt * 4 + jb) * 2 + ks) * 512 + l * 8);
    // p2c A-operand: NAMED registers, w-dependent ADDRESS
    const bf16_t* kwp = kFb + ((size_t)(jt * 4 + w) * 2) * 512 + l * 8;
    const bf16x8 kw0 = *reinterpret_cast<const bf16x8*>(kwp);
    const bf16x8 kw1 = *reinterpret_cast<const bf16x8*>(kwp + 512);

    const int dbase = 4 * qt - 4 * jt + 31 - w;   // p2c window base dblk (in [0,59])

    __builtin_amdgcn_s_setprio(1);
    // QK^T
    f32x4 sfr[4];
#pragma unroll
    for (int n = 0; n < 4; ++n) {
      f32x4 t = {};
      t = MFMA16(aq0, kA[n][0], t);
      t = MFMA16(aq1, kA[n][1], t);
      sfr[n] = t;
    }

    // c2p: dblk = W + w + cg; ring iff w+cg >= 4 (wave-uniform); store [u][ip] b64
#pragma unroll
    for (int cg = 0; cg < 5; ++cg) {
      const int dblk = W + w + cg;
      bf16x8 p0, p1;
      if (w + cg >= 4) {
        const bf16_t* pp = pkS + (dblk & 7) * 1024 + l * 8;
        p0 = *reinterpret_cast<const bf16x8*>(pp);
        p1 = *reinterpret_cast<const bf16x8*>(pp + 512);
      } else {
        const bf16_t* pp = pkFb + ((size_t)dblk * 2) * 512 + l * 8;
        p0 = *reinterpret_cast<const bf16x8*>(pp);
        p1 = *reinterpret_cast<const bf16x8*>(pp + 512);
      }
      f32x4 d = {};
      d = MFMA16(aq0, p0, d);
      d = MFMA16(aq1, p1, d);
      bf16x4 dv;
#pragma unroll
      for (int r = 0; r < 4; ++r) dv[r] = (bf16_t)d[r];
      *reinterpret_cast<bf16x4*>(&DcpT[w][cg * 16 + li][gr * 4]) = dv;
    }

    // p2c (shared): wave w computes jj in [w*16,+16) with A = kw0/kw1;
    // B-frags direct from global (L2-hot). Store D2p[jj][ii+16] unguarded.
#pragma unroll
    for (int cg = 0; cg < 5; ++cg) {
      const bf16_t* qq = pqFb + ((size_t)(dbase + cg) * 2) * 512 + l * 8;
      bf16x8 q0 = *reinterpret_cast<const bf16x8*>(qq);
      bf16x8 q1 = *reinterpret_cast<const bf16x8*>(qq + 512);
      f32x4 d = {};
      d = MFMA16(kw0, q0, d);
      d = MFMA16(kw1, q1, d);
#pragma unroll
      for (int r = 0; r < 4; ++r) {
        const int jp = gr * 4 + r;
        D2p[w * 16 + jp][cg * 16 + li + jp + 1] = (bf16_t)d[r];
      }
    }
    __builtin_amdgcn_s_setprio(0);

    // V B-frags (global, issued early; consumed at PV after the barrier)
    bf16x8 vf[2][4];
#pragma unroll
    for (int ks = 0; ks < 2; ++ks)
#pragma unroll
      for (int n2 = 0; n2 < 4; ++n2)
        vf[ks][n2] = *reinterpret_cast<const bf16x8*>(
            vFb + (((size_t)(jt * 2 + ks) * 4 + n2) * 512) + l * 8);

    // mid barrier: D2p writes visible
    asm volatile("s_waitcnt lgkmcnt(0)" ::: "memory");
    __builtin_amdgcn_s_barrier();
    __builtin_amdgcn_sched_barrier(0);

    // gather diagonals + softmax + Pl
#pragma unroll
    for (int n = 0; n < 4; ++n) {
      const bf16x4 pvv = *reinterpret_cast<const bf16x4*>(&D2p[n * 16 + li][w * 16 + gr * 4 + 16]);
#pragma unroll
      for (int r = 0; r < 4; ++r) {
        const int ip = gr * 4 + r;
        const int u = ip + 63 - n * 16 - li;  // in [ip, ip+63] subset [0,79)
        const float c2 = (float)DcpT[w][u][ip];
        const float s2 = sfr[n][r] + c2 + (float)pvv[r] - MCONST;
        const float pe = __builtin_amdgcn_exp2f(s2);
        lsum[r] += pe;
        int ch = (n * 2 + (li >> 3)) * 16 + gr * 4 + r;
        ch ^= ((ch >> 3) & 7);
        Pl[w][ch * 8 + (li & 7)] = (bf16_t)pe;
      }
    }

    // PV (Pl per-wave; vf already in registers)
    __builtin_amdgcn_s_setprio(1);
#pragma unroll
    for (int ks = 0; ks < 2; ++ks) {
      int chA = (ks * 4 + gr) * 16 + li;
      chA ^= ((chA >> 3) & 7);
      bf16x8 ap = *reinterpret_cast<const bf16x8*>(Pl[w] + chA * 8);
#pragma unroll
      for (int n2 = 0; n2 < 4; ++n2)
        acc[n2] = MFMA16(ap, vf[ks][n2], acc[n2]);
    }
    __builtin_amdgcn_s_setprio(0);
  }

  // reduce lsum across the 16 li lanes, normalize, store
#pragma unroll
  for (int mm = 1; mm < 16; mm <<= 1)
#pragma unroll
    for (int r = 0; r < 4; ++r)
      lsum[r] += __shfl_xor(lsum[r], mm, 64);
  float invl[4];
#pragma unroll
  for (int r = 0; r < 4; ++r) invl[r] = 1.0f / lsum[r];

#pragma unroll
  for (int n2 = 0; n2 < 4; ++n2)
#pragma unroll
    for (int r = 0; r < 4; ++r) {
      const int i = i0 + w * 16 + gr * 4 + r;
      const int wcol = n2 * 16 + li;
      out[(size_t)(b * 512 + i) * 1024 + h * 64 + wcol] = acc[n2][r] * invl[r];
    }
}

// ---------------------------------------------------------------- launch
extern "C" void kernel_launch(void* const* d_in, const int* in_sizes, int n_in,
                              void* d_out, int out_size, void* d_ws, size_t ws_size,
                              hipStream_t stream) {
  (void)in_sizes; (void)n_in; (void)out_size; (void)ws_size;
  const float* x   = (const float*)d_in[0];
  const float* rel = (const float*)d_in[1];
  const float* Wq  = (const float*)d_in[2];
  const float* bq  = (const float*)d_in[3];
  const float* Wk  = (const float*)d_in[4];
  const float* bk  = (const float*)d_in[5];
  const float* Wv  = (const float*)d_in[6];
  const float* bv  = (const float*)d_in[7];
  float* out = (float*)d_out;

  bf16_t* ws  = (bf16_t*)d_ws;
  bf16_t* xb  = ws;                 // 4 M elems
  bf16_t* wqb = xb + 4194304;       // 1 M each
  bf16_t* wkb = wqb + 1048576;
  bf16_t* wvb = wkb + 1048576;
  bf16_t* reb = wvb + 1048576;
  bf16_t* qFb = reb + 1048576;      // 4 M each (fragment-ordered)
  bf16_t* kFb = qFb + 4194304;
  bf16_t* vFb = kFb + 4194304;
  bf16_t* pkFb = vFb + 4194304;     // 1 M each
  bf16_t* pqFb = pkFb + 1048576;    // total ws ~44 MB

  cvt_all<<<4096, 256, 0, stream>>>(x, rel, Wq, Wk, Wv, ws);
  gemm_qkv<<<448, 512, 0, stream>>>(xb, reb, wqb, wkb, wvb,
                                    bq, bk, bv, qFb, kFb, vFb, pkFb, pqFb);
  attn_v7<<<1024, 256, 0, stream>>>(qFb, kFb, vFb, pkFb, pqFb, out);
}

// Round 18
// 95.021 us; speedup vs baseline: 1.2049x; 1.2049x over previous
//
#include <hip/hip_runtime.h>

// FTDisentangledMHA: B=8, S=512, D=1024, H=16, Wd=64, MAX_REL=512 (span==S)
// scores(i,j) = scale*(q_i.k_j + q_i.pk[d] + k_j.pq[d]), d = i-j+511 (never clipped).
// q,pq pre-scaled by scale*log2e; softmax = exp2 with fixed max M=3.
// R18 = R16 (champion) + K-frag LDS ring: K's fragment layout is linear per jt
// (4096 elems at kFb+jt*4096), staged one jt ahead via global_load_lds into a
// 2-buffer ring -> kA/kw become LDS reads of landed data (QK^T fed without
// exposed global latency). pk ring + direct pq unchanged from R16.

typedef __bf16 bf16_t;
typedef __bf16 bf16x8 __attribute__((ext_vector_type(8)));
typedef __bf16 bf16x4 __attribute__((ext_vector_type(4)));
typedef float  f32x4  __attribute__((ext_vector_type(4)));

#define MFMA16(a, b, c) __builtin_amdgcn_mfma_f32_16x16x32_bf16((a), (b), (c), 0, 0, 0)
#define S2SCALE 0.10411754f   // (1/sqrt(192)) * log2(e)
#define MCONST  4.3280851f    // 3 * log2(e)

__device__ __forceinline__ void gload_lds16(const bf16_t* g, bf16_t* lds) {
  __builtin_amdgcn_global_load_lds(
      (const __attribute__((address_space(1))) void*)g,
      (__attribute__((address_space(3))) void*)lds, 16, 0, 0);
}

// ---------------------------------------------------------------- fp32 -> bf16 (all 5 arrays)
__global__ __launch_bounds__(256) void cvt_all(
    const float* __restrict__ x, const float* __restrict__ rel,
    const float* __restrict__ wq, const float* __restrict__ wk, const float* __restrict__ wv,
    bf16_t* __restrict__ out) {
  const size_t i = ((size_t)blockIdx.x * 256 + threadIdx.x) * 8;
  const float* src; size_t off;
  if (i < 4194304) { src = x; off = i; }
  else {
    size_t j = i - 4194304; int sel = (int)(j >> 20); off = j & 1048575;
    src = sel == 0 ? wq : sel == 1 ? wk : sel == 2 ? wv : rel;
  }
  float4 v0 = *reinterpret_cast<const float4*>(src + off);
  float4 v1 = *reinterpret_cast<const float4*>(src + off + 4);
  bf16x8 o;
  o[0] = (bf16_t)v0.x; o[1] = (bf16_t)v0.y; o[2] = (bf16_t)v0.z; o[3] = (bf16_t)v0.w;
  o[4] = (bf16_t)v1.x; o[5] = (bf16_t)v1.y; o[6] = (bf16_t)v1.z; o[7] = (bf16_t)v1.w;
  *reinterpret_cast<bf16x8*>(out + i) = o;
}

// ------------------------------------------------- 128x256-tile 8-phase projection GEMM
// 448 blocks (2/CU). Epilogue writes FRAGMENT-ordered outputs (reader: attn_v8):
//  kind 1 (q,k): flat = (((b16h)*32 + (j>>4))*2 + ks)*512 + ((j&15)|(kg<<4))*8 + e
//  kind 3 (pk,pq): flat = ((h*64 + (d>>4))*2 + ks)*512 + ((d&15)|(kg<<4))*8 + e
//  kind 2 (v): flat = (((b16h)*16 + (j>>5))*4 + n2)*512 + ((w&15)|(((j>>3)&3)<<4))*8 + (j&7)
__device__ __forceinline__ void stage_tileB(const bf16_t* base, int T, bf16_t* lds, int tid) {
#pragma unroll
  for (int i = 0; i < 2; ++i) {
    const int c = tid + i * 512;
    const int row = c >> 2, kg = (c & 3) ^ (row & 3);
    gload_lds16(base + (size_t)row * 1024 + T * 32 + kg * 8, lds + c * 8);
  }
}
__device__ __forceinline__ void stage_tileA(const bf16_t* base, int T, bf16_t* lds, int tid) {
  const int row = tid >> 2, kg = (tid & 3) ^ (row & 3);
  gload_lds16(base + (size_t)row * 1024 + T * 32 + kg * 8, lds + tid * 8);
}

#define VMW2 asm volatile("s_waitcnt vmcnt(2)" ::: "memory")
#define VMW0 asm volatile("s_waitcnt vmcnt(0)" ::: "memory")
#define NOPS ((void)0)

// phase: 2 A-frags (FH half of the wave's 64 rows) x 4 B-frags = 8 MFMA
#define PH_BODY(AB, BB, FH, READB, STAGE_STMT, WAIT_STMT)                               \
  {                                                                                     \
    if (READB) {                                                                        \
      _Pragma("unroll") for (int n_ = 0; n_ < 4; ++n_)                                  \
        bfr[n_] = *reinterpret_cast<const bf16x8*>(                                     \
            (BB) + (((wn * 64 + n_ * 16 + li) * 4 + (gr ^ (li & 3))) * 8));             \
    }                                                                                   \
    bf16x8 af_[2];                                                                      \
    _Pragma("unroll") for (int a_ = 0; a_ < 2; ++a_)                                    \
      af_[a_] = *reinterpret_cast<const bf16x8*>(                                       \
          (AB) + (((wm * 64 + ((FH) * 2 + a_) * 16 + li) * 4 + (gr ^ (li & 3))) * 8));  \
    STAGE_STMT;                                                                         \
    __builtin_amdgcn_s_barrier();                                                       \
    asm volatile("s_waitcnt lgkmcnt(0)" ::: "memory");                                  \
    __builtin_amdgcn_sched_barrier(0);                                                  \
    __builtin_amdgcn_s_setprio(1);                                                      \
    _Pragma("unroll") for (int a_ = 0; a_ < 2; ++a_)                                    \
      _Pragma("unroll") for (int n_ = 0; n_ < 4; ++n_)                                  \
        acc[(FH) * 2 + a_][n_] = MFMA16(af_[a_], bfr[n_], acc[(FH) * 2 + a_][n_]);      \
    __builtin_amdgcn_s_setprio(0);                                                      \
    WAIT_STMT;                                                                          \
    __builtin_amdgcn_s_barrier();                                                       \
    __builtin_amdgcn_sched_barrier(0);                                                  \
  }

__global__ __launch_bounds__(512, 2) void gemm_qkv(
    const bf16_t* __restrict__ xb, const bf16_t* __restrict__ reb,
    const bf16_t* __restrict__ wqb, const bf16_t* __restrict__ wkb, const bf16_t* __restrict__ wvb,
    const float* __restrict__ bq, const float* __restrict__ bk, const float* __restrict__ bv,
    bf16_t* __restrict__ qF, bf16_t* __restrict__ kF, bf16_t* __restrict__ vF,
    bf16_t* __restrict__ pkF, bf16_t* __restrict__ pqF) {
  __shared__ bf16_t Abuf[2][4096];   // 128 x 32
  __shared__ bf16_t Bbuf[2][8192];   // 256 x 32

  const int bid0 = blockIdx.x;
  const int bid = (bid0 & 7) * 56 + (bid0 >> 3);  // 448 = 8*56, bijective XCD chunks
  const int tid = threadIdx.x;
  const int wave = tid >> 6;
  const int wm = wave >> 2, wn = wave & 3;
  const int l = tid & 63, li = l & 15, gr = l >> 4;

  const bf16_t* Abase; const bf16_t* Bbase; const float* bias; float sc;
  bf16_t* Cout; int row0, col0, kind;
  if (bid < 384) {  // main: x (4096 rows, 32 tiles of 128) x [Wq|Wk|Wv] (3072)
    const int bx = bid / 12, by = bid % 12;
    Abase = xb + (size_t)bx * 131072; row0 = bx * 128;
    const int wsel = by >> 2;
    Bbase = (wsel == 0 ? wqb : wsel == 1 ? wkb : wvb) + (size_t)(by & 3) * 262144;
    bias = wsel == 0 ? bq : wsel == 1 ? bk : bv;
    sc = wsel == 0 ? S2SCALE : 1.f;
    Cout = wsel == 0 ? qF : wsel == 1 ? kF : vF;
    kind = wsel == 2 ? 2 : 1;
    col0 = (by & 3) * 256;
  } else {  // pos: re (1024 rows, 8 tiles) x [Wk|Wq] (2048)
    const int p = bid - 384;
    const int bx = p >> 3, by = p & 7;
    Abase = reb + (size_t)bx * 131072; row0 = bx * 128;
    const int wsel = by >> 2;
    Bbase = (wsel == 0 ? wkb : wqb) + (size_t)(by & 3) * 262144;
    bias = wsel == 0 ? bk : bq;
    sc = wsel == 0 ? 1.f : S2SCALE;
    Cout = wsel == 0 ? pkF : pqF;
    kind = 3;
    col0 = (by & 3) * 256;
  }

  f32x4 acc[4][4] = {};
  bf16x8 bfr[4];

  // prologue: A0(1), B0(2), B1(2) in flight; vmcnt(2) waits A0+B0, leaves B1 flying
  stage_tileA(Abase, 0, Abuf[0], tid);
  stage_tileB(Bbase, 0, Bbuf[0], tid);
  stage_tileB(Bbase, 1, Bbuf[1], tid);
  VMW2;
  __builtin_amdgcn_s_barrier();
  __builtin_amdgcn_sched_barrier(0);

  for (int t = 0; t < 15; ++t) {
    const int T0 = 2 * t;
    PH_BODY(Abuf[0], Bbuf[0], 0, true,  stage_tileA(Abase, T0 + 1, Abuf[1], tid), NOPS);
    PH_BODY(Abuf[0], Bbuf[0], 1, false, stage_tileB(Bbase, T0 + 2, Bbuf[0], tid), VMW2);
    PH_BODY(Abuf[1], Bbuf[1], 0, true,  stage_tileA(Abase, T0 + 2, Abuf[0], tid), NOPS);
    PH_BODY(Abuf[1], Bbuf[1], 1, false, stage_tileB(Bbase, T0 + 3, Bbuf[1], tid), VMW2);
  }
  // peeled t=15 (tiles 30,31): only A(31) left to stage
  PH_BODY(Abuf[0], Bbuf[0], 0, true,  stage_tileA(Abase, 31, Abuf[1], tid), NOPS);
  PH_BODY(Abuf[0], Bbuf[0], 1, false, NOPS, VMW0);
  PH_BODY(Abuf[1], Bbuf[1], 0, true,  NOPS, NOPS);
  PH_BODY(Abuf[1], Bbuf[1], 1, false, NOPS, NOPS);

  // epilogue: fragment-ordered stores
#pragma unroll
  for (int a = 0; a < 4; ++a)
#pragma unroll
    for (int n = 0; n < 4; ++n) {
      const int col = col0 + wn * 64 + n * 16 + li;
      const int h_ = col >> 6, kk = col & 63;
      const float bv_ = bias[col];
      const int rowb = row0 + wm * 64 + a * 16 + gr * 4;
      if (kind == 2) {
        bf16x4 ov;
#pragma unroll
        for (int r = 0; r < 4; ++r) ov[r] = (bf16_t)((acc[a][n][r] + bv_) * sc);
        const int j = rowb & 511, b_ = rowb >> 9;
        const size_t flat = ((((size_t)(b_ * 16 + h_) * 16 + (j >> 5)) * 4 + (kk >> 4)) * 512) +
                            ((size_t)((kk & 15) | (((j >> 3) & 3) << 4))) * 8 + (j & 7);
        *reinterpret_cast<bf16x4*>(Cout + flat) = ov;
      } else {
        const int ks = kk >> 5, kg3 = (kk >> 3) & 3, e = kk & 7;
#pragma unroll
        for (int r = 0; r < 4; ++r) {
          const int row = rowb + r;
          const int blk = (kind == 1) ? (((row >> 9) * 16 + h_) * 32 + ((row & 511) >> 4))
                                      : (h_ * 64 + (row >> 4));
          const size_t flat = ((size_t)blk * 2 + ks) * 512 + ((row & 15) | (kg3 << 4)) * 8 + e;
          Cout[flat] = (bf16_t)((acc[a][n][r] + bv_) * sc);
        }
      }
    }
}

// ---------------------------------------------------------------- fused attention
// 1024 blocks = (b,h,qt); 4 waves. pk in 12-slot LDS ring; K frags in a 2-buffer
// LDS ring staged one jt ahead; pq frags direct from global (L2-hot). 2 barriers/jt.
__global__ __launch_bounds__(256, 2) void attn_v8(
    const bf16_t* __restrict__ qF, const bf16_t* __restrict__ kF,
    const bf16_t* __restrict__ vF, const bf16_t* __restrict__ pkF,
    const bf16_t* __restrict__ pqF, float* __restrict__ out) {
  const int bid0 = blockIdx.x;
  const int bid = (bid0 & 7) * 128 + (bid0 >> 3);  // XCD-contiguous (b,h)
  const int qt = bid & 7;
  const int h = (bid >> 3) & 15;
  const int b = bid >> 7;
  const int i0 = qt * 64;
  const int tid = threadIdx.x;
  const int l = tid & 63;
  const int w = tid >> 6;
  const int li = l & 15, gr = l >> 4;

  __shared__ bf16_t pkS[12288];       // 12 slots x 1024 elems (dblk%12)       24 KB
  __shared__ bf16_t KsR[2][4096];     // K frag ring (jt parity)               16 KB
  __shared__ bf16_t Pl[4][1024];      // per-wave P A-frags (kchunk-swizzled)   8 KB
  __shared__ bf16_t DcpT[4][80][20];  // per-wave c2p [u_local][ip]           12.8 KB
  __shared__ bf16_t D2p[64][84];      // p2c [jj][ii+16] (unguarded)          10.5 KB

  const bf16_t* qFb = qF + (size_t)(b * 16 + h) * 32768;
  const bf16_t* kFb = kF + (size_t)(b * 16 + h) * 32768;
  const bf16_t* vFb = vF + (size_t)(b * 16 + h) * 32768;
  const bf16_t* pkFb = pkF + (size_t)h * 65536;
  const bf16_t* pqFb = pqF + (size_t)h * 65536;

  // Q A-frags (rows i0 + w*16 .. +15), coalesced
  const bf16x8 aq0 = *reinterpret_cast<const bf16x8*>(qFb + ((size_t)(qt * 4 + w) * 2 + 0) * 512 + l * 8);
  const bf16x8 aq1 = *reinterpret_cast<const bf16x8*>(qFb + ((size_t)(qt * 4 + w) * 2 + 1) * 512 + l * 8);

  // prologue: stage jt=0 pk window dblks W0..W0+7 (4 chunks/thread) + K(0) (2 chunks/thread)
  {
    const int W0 = 4 * qt + 28;
#pragma unroll
    for (int i2 = 0; i2 < 4; ++i2) {
      const int c = i2 * 256 + tid;         // 0..1023
      const int dblk = W0 + (c >> 7);
      const int inner = c & 127;
      const int slot = dblk % 12;
      gload_lds16(pkFb + (size_t)dblk * 1024 + inner * 8, pkS + slot * 1024 + inner * 8);
    }
#pragma unroll
    for (int i2 = 0; i2 < 2; ++i2) {
      const int c = i2 * 256 + tid;         // 0..511 (K tile jt=0: linear 4096 elems)
      gload_lds16(kFb + c * 8, KsR[0] + c * 8);
    }
  }

  f32x4 acc[4] = {};
  float lsum[4] = {0.f, 0.f, 0.f, 0.f};

  for (int jt = 0; jt < 8; ++jt) {
    const int cur = jt & 1;
    const int W = 4 * qt - 4 * jt + 28;   // pk window base dblk, in [0,56]

    // top barrier: pk ring slots + K ring buffer for this jt staged; prev D2p reads done
    VMW0;
    __builtin_amdgcn_s_barrier();
    __builtin_amdgcn_sched_barrier(0);

    // prefetch jt+1: 4 new pk dblks (2 chunks/thread) + K(jt+1) (2 chunks/thread)
    if (jt < 7) {
      const int Wn = W - 4;
#pragma unroll
      for (int i2 = 0; i2 < 2; ++i2) {
        const int c = i2 * 256 + tid;       // 0..511
        const int dblk = Wn + (c >> 7);
        const int inner = c & 127;
        const int slot = dblk % 12;
        gload_lds16(pkFb + (size_t)dblk * 1024 + inner * 8, pkS + slot * 1024 + inner * 8);
      }
#pragma unroll
      for (int i2 = 0; i2 < 2; ++i2) {
        const int c = i2 * 256 + tid;       // 0..511
        gload_lds16(kFb + (size_t)(jt + 1) * 4096 + c * 8, KsR[cur ^ 1] + c * 8);
      }
    }

    // K frags from LDS ring (prefetched; conflict-free contiguous b128)
    bf16x8 kA[4][2];
#pragma unroll
    for (int jb = 0; jb < 4; ++jb)
#pragma unroll
      for (int ks = 0; ks < 2; ++ks)
        kA[jb][ks] = *reinterpret_cast<const bf16x8*>(KsR[cur] + (jb * 2 + ks) * 512 + l * 8);
    // p2c A-operand: NAMED registers, w-dependent LDS address
    const bf16_t* kwp = KsR[cur] + (w * 2) * 512 + l * 8;
    const bf16x8 kw0 = *reinterpret_cast<const bf16x8*>(kwp);
    const bf16x8 kw1 = *reinterpret_cast<const bf16x8*>(kwp + 512);

    const int dbase = 4 * qt - 4 * jt + 31 - w;   // p2c window base dblk (in [0,59])

    __builtin_amdgcn_s_setprio(1);
    // QK^T
    f32x4 sfr[4];
#pragma unroll
    for (int n = 0; n < 4; ++n) {
      f32x4 t = {};
      t = MFMA16(aq0, kA[n][0], t);
      t = MFMA16(aq1, kA[n][1], t);
      sfr[n] = t;
    }

    // c2p: B-frags from pk ring; store transposed [u][ip] (b64)
    int sc = (W + w) % 12;
#pragma unroll
    for (int cg = 0; cg < 5; ++cg) {
      int slot = sc + cg; if (slot >= 12) slot -= 12;
      const bf16_t* pp = pkS + slot * 1024 + l * 8;
      bf16x8 p0 = *reinterpret_cast<const bf16x8*>(pp);
      bf16x8 p1 = *reinterpret_cast<const bf16x8*>(pp + 512);
      f32x4 d = {};
      d = MFMA16(aq0, p0, d);
      d = MFMA16(aq1, p1, d);
      bf16x4 dv;
#pragma unroll
      for (int r = 0; r < 4; ++r) dv[r] = (bf16_t)d[r];
      *reinterpret_cast<bf16x4*>(&DcpT[w][cg * 16 + li][gr * 4]) = dv;
    }

    // p2c (shared): wave w computes jj in [w*16,+16) with A = kw0/kw1;
    // B-frags DIRECT from global (L2-hot). Store D2p[jj][ii+16] unguarded.
#pragma unroll
    for (int cg = 0; cg < 5; ++cg) {
      const bf16_t* qq = pqFb + ((size_t)(dbase + cg) * 2) * 512 + l * 8;
      bf16x8 q0 = *reinterpret_cast<const bf16x8*>(qq);
      bf16x8 q1 = *reinterpret_cast<const bf16x8*>(qq + 512);
      f32x4 d = {};
      d = MFMA16(kw0, q0, d);
      d = MFMA16(kw1, q1, d);
#pragma unroll
      for (int r = 0; r < 4; ++r) {
        const int jp = gr * 4 + r;
        D2p[w * 16 + jp][cg * 16 + li + jp + 1] = (bf16_t)d[r];
      }
    }
    __builtin_amdgcn_s_setprio(0);

    // V B-frags (global, issued early; consumed at PV after the barrier)
    bf16x8 vf[2][4];
#pragma unroll
    for (int ks = 0; ks < 2; ++ks)
#pragma unroll
      for (int n2 = 0; n2 < 4; ++n2)
        vf[ks][n2] = *reinterpret_cast<const bf16x8*>(
            vFb + (((size_t)(jt * 2 + ks) * 4 + n2) * 512) + l * 8);

    // mid barrier: D2p writes visible
    asm volatile("s_waitcnt lgkmcnt(0)" ::: "memory");
    __builtin_amdgcn_s_barrier();
    __builtin_amdgcn_sched_barrier(0);

    // gather diagonals + softmax + Pl
#pragma unroll
    for (int n = 0; n < 4; ++n) {
      const bf16x4 pvv = *reinterpret_cast<const bf16x4*>(&D2p[n * 16 + li][w * 16 + gr * 4 + 16]);
#pragma unroll
      for (int r = 0; r < 4; ++r) {
        const int ip = gr * 4 + r;
        const int u = ip + 63 - n * 16 - li;  // in [ip, ip+63] subset [0,79)
        const float c2 = (float)DcpT[w][u][ip];
        const float s2 = sfr[n][r] + c2 + (float)pvv[r] - MCONST;
        const float pe = __builtin_amdgcn_exp2f(s2);
        lsum[r] += pe;
        int ch = (n * 2 + (li >> 3)) * 16 + gr * 4 + r;
        ch ^= ((ch >> 3) & 7);
        Pl[w][ch * 8 + (li & 7)] = (bf16_t)pe;
      }
    }

    // PV (Pl per-wave; vf already in registers)
    __builtin_amdgcn_s_setprio(1);
#pragma unroll
    for (int ks = 0; ks < 2; ++ks) {
      int chA = (ks * 4 + gr) * 16 + li;
      chA ^= ((chA >> 3) & 7);
      bf16x8 ap = *reinterpret_cast<const bf16x8*>(Pl[w] + chA * 8);
#pragma unroll
      for (int n2 = 0; n2 < 4; ++n2)
        acc[n2] = MFMA16(ap, vf[ks][n2], acc[n2]);
    }
    __builtin_amdgcn_s_setprio(0);
  }

  // reduce lsum across the 16 li lanes, normalize, store
#pragma unroll
  for (int mm = 1; mm < 16; mm <<= 1)
#pragma unroll
    for (int r = 0; r < 4; ++r)
      lsum[r] += __shfl_xor(lsum[r], mm, 64);
  float invl[4];
#pragma unroll
  for (int r = 0; r < 4; ++r) invl[r] = 1.0f / lsum[r];

#pragma unroll
  for (int n2 = 0; n2 < 4; ++n2)
#pragma unroll
    for (int r = 0; r < 4; ++r) {
      const int i = i0 + w * 16 + gr * 4 + r;
      const int wcol = n2 * 16 + li;
      out[(size_t)(b * 512 + i) * 1024 + h * 64 + wcol] = acc[n2][r] * invl[r];
    }
}

// ---------------------------------------------------------------- launch
extern "C" void kernel_launch(void* const* d_in, const int* in_sizes, int n_in,
                              void* d_out, int out_size, void* d_ws, size_t ws_size,
                              hipStream_t stream) {
  (void)in_sizes; (void)n_in; (void)out_size; (void)ws_size;
  const float* x   = (const float*)d_in[0];
  const float* rel = (const float*)d_in[1];
  const float* Wq  = (const float*)d_in[2];
  const float* bq  = (const float*)d_in[3];
  const float* Wk  = (const float*)d_in[4];
  const float* bk  = (const float*)d_in[5];
  const float* Wv  = (const float*)d_in[6];
  const float* bv  = (const float*)d_in[7];
  float* out = (float*)d_out;

  bf16_t* ws  = (bf16_t*)d_ws;
  bf16_t* xb  = ws;                 // 4 M elems
  bf16_t* wqb = xb + 4194304;       // 1 M each
  bf16_t* wkb = wqb + 1048576;
  bf16_t* wvb = wkb + 1048576;
  bf16_t* reb = wvb + 1048576;
  bf16_t* qFb = reb + 1048576;      // 4 M each (fragment-ordered)
  bf16_t* kFb = qFb + 4194304;
  bf16_t* vFb = kFb + 4194304;
  bf16_t* pkFb = vFb + 4194304;     // 1 M each
  bf16_t* pqFb = pkFb + 1048576;    // total ws ~44 MB

  cvt_all<<<4096, 256, 0, stream>>>(x, rel, Wq, Wk, Wv, ws);
  gemm_qkv<<<448, 512, 0, stream>>>(xb, reb, wqb, wkb, wvb,
                                    bq, bk, bv, qFb, kFb, vFb, pkFb, pqFb);
  attn_v8<<<1024, 256, 0, stream>>>(qFb, kFb, vFb, pkFb, pqFb, out);
}